// Round 2
// baseline (805.992 us; speedup 1.0000x reference)
//
#include <hip/hip_runtime.h>
#include <hip/hip_bf16.h>

// Problem constants (fixed by setup_inputs)
#define B_    2
#define LQ    21760
#define NROW  (B_*LQ)      // 43520 = 340*128
#define CDIM  256
#define DFF   1024

typedef __attribute__((ext_vector_type(8))) short bf16x8;
typedef __attribute__((ext_vector_type(4))) float f32x4;

static __device__ __forceinline__ ushort f2bf(float f) {
    union { float f; unsigned u; } v; v.f = f;
    unsigned u = v.u;
    return (ushort)((u + 0x7fffu + ((u >> 16) & 1u)) >> 16);
}
static __device__ __forceinline__ float bf2f(ushort h) {
    union { unsigned u; float f; } v; v.u = ((unsigned)h) << 16; return v.f;
}

// ---------------------------------------------------------------- elementwise
// q = src + pos; emit bf16 copies of src and q
__global__ void addpos_cast(const float* __restrict__ src, const float* __restrict__ pos,
                            ushort* __restrict__ s16, ushort* __restrict__ q16, int n4) {
    int i = blockIdx.x * blockDim.x + threadIdx.x;
    int stride = gridDim.x * blockDim.x;
    const float4* s4 = (const float4*)src;
    const float4* p4 = (const float4*)pos;
    for (; i < n4; i += stride) {
        float4 s = s4[i], p = p4[i];
        ushort4 a, b;
        a.x = f2bf(s.x); a.y = f2bf(s.y); a.z = f2bf(s.z); a.w = f2bf(s.w);
        b.x = f2bf(s.x + p.x); b.y = f2bf(s.y + p.y);
        b.z = f2bf(s.z + p.z); b.w = f2bf(s.w + p.w);
        ((ushort4*)s16)[i] = a;
        ((ushort4*)q16)[i] = b;
    }
}

// Wt[n*K+k] = bf16(W[k*N+n])   (tiny, one-off)
__global__ void wtrans(const float* __restrict__ W, ushort* __restrict__ Wt, int K, int N) {
    int i = blockIdx.x * blockDim.x + threadIdx.x;
    int total = K * N;
    for (; i < total; i += gridDim.x * blockDim.x) {
        int n = i / K, k = i - n * K;
        Wt[i] = f2bf(W[(size_t)k * N + n]);
    }
}

// ---------------------------------------------------------------- GEMM
// C[M][N] = A[M][K] * B[K][N] (+bias, opt relu), A bf16 row-major, Bt = B^T bf16 [N][K]
// Block tile 128x64, 4 waves (2x2), per-wave 64x32 via 4x2 16x16x32 MFMA frags.
template<int RELU, int OUTBF16>
__global__ __launch_bounds__(256) void gemm_bf16(
    const ushort* __restrict__ A, const ushort* __restrict__ Bt,
    const float* __restrict__ bias,
    float* __restrict__ Cf, ushort* __restrict__ Ch, int K, int N) {
    __shared__ __align__(16) ushort As[128][40];  // +8 pad: 80B row stride -> 2-way (free)
    __shared__ __align__(16) ushort Bs[64][40];
    const int tid  = threadIdx.x;
    const int bm   = blockIdx.x * 128;
    const int bn   = blockIdx.y * 64;
    const int w    = tid >> 6, lane = tid & 63;
    const int wm   = (w >> 1) * 64, wn = (w & 1) * 32;
    const int lr   = lane & 15, lk = lane >> 4;
    const int ar   = tid >> 2, ac = (tid & 3) * 8;   // staging coords

    f32x4 acc[4][2] = {};

    for (int k0 = 0; k0 < K; k0 += 32) {
        *(uint4*)&As[ar][ac]      = *(const uint4*)&A[(size_t)(bm + ar) * K + k0 + ac];
        *(uint4*)&As[ar + 64][ac] = *(const uint4*)&A[(size_t)(bm + ar + 64) * K + k0 + ac];
        *(uint4*)&Bs[ar][ac]      = *(const uint4*)&Bt[(size_t)(bn + ar) * K + k0 + ac];
        __syncthreads();
        bf16x8 af[4], bfr[2];
        #pragma unroll
        for (int m = 0; m < 4; m++) af[m]  = *(const bf16x8*)&As[wm + m * 16 + lr][lk * 8];
        #pragma unroll
        for (int n = 0; n < 2; n++) bfr[n] = *(const bf16x8*)&Bs[wn + n * 16 + lr][lk * 8];
        #pragma unroll
        for (int m = 0; m < 4; m++)
            #pragma unroll
            for (int n = 0; n < 2; n++)
                acc[m][n] = __builtin_amdgcn_mfma_f32_16x16x32_bf16(af[m], bfr[n], acc[m][n], 0, 0, 0);
        __syncthreads();
    }
    // Epilogue. D: col = lane&15, row = (lane>>4)*4 + i
    #pragma unroll
    for (int m = 0; m < 4; m++) {
        int row = bm + wm + m * 16 + lk * 4;
        #pragma unroll
        for (int n = 0; n < 2; n++) {
            int col = bn + wn + n * 16 + lr;
            float bb = bias ? bias[col] : 0.f;
            #pragma unroll
            for (int i = 0; i < 4; i++) {
                float v = acc[m][n][i] + bb;
                if (RELU) v = v > 0.f ? v : 0.f;
                if (OUTBF16) Ch[(size_t)(row + i) * N + col] = f2bf(v);
                else         Cf[(size_t)(row + i) * N + col] = v;
            }
        }
    }
}

// ---------------------------------------------------------------- deform attn
// 1 block per (b, query). tid: h = tid>>5 (8 heads), c = tid&31 (32 channels)
__global__ __launch_bounds__(256) void deform_attn(
    const float* __restrict__ value,   // [NROW][256]
    const float* __restrict__ offs,    // [NROW][256] = [NH][NL][NP][2]
    const float* __restrict__ alog,    // [NROW][128] = [NH][16]
    const float* __restrict__ rp,      // [NROW][4][2]
    ushort* __restrict__ out16) {      // [NROW][256] bf16
    const int row = blockIdx.x;
    const int b   = row / LQ;
    const int tid = threadIdx.x;
    const int h   = tid >> 5, c = tid & 31;

    const float* lg = alog + (size_t)row * 128 + h * 16;
    float lv[16], mx = -1e30f;
    #pragma unroll
    for (int j = 0; j < 16; j++) { lv[j] = lg[j]; mx = fmaxf(mx, lv[j]); }
    float sum = 0.f;
    #pragma unroll
    for (int j = 0; j < 16; j++) { lv[j] = __expf(lv[j] - mx); sum += lv[j]; }
    const float inv = 1.f / sum;

    const int Hs[4] = {128, 64, 32, 16};
    const int st[4] = {0, 16384, 20480, 21504};
    const float* of   = offs + (size_t)row * 256 + h * 32;
    const float* rpr  = rp + (size_t)row * 8;
    const float* vb   = value + (size_t)b * LQ * 256 + h * 32 + c;

    float acc = 0.f;
    #pragma unroll
    for (int l = 0; l < 4; l++) {
        const int H_ = Hs[l], W_ = Hs[l], s0 = st[l];
        float rx = rpr[l * 2], ry = rpr[l * 2 + 1];
        #pragma unroll
        for (int p = 0; p < 4; p++) {
            float ox = of[(l * 4 + p) * 2], oy = of[(l * 4 + p) * 2 + 1];
            float x = rx * W_ + ox - 0.5f;
            float y = ry * H_ + oy - 0.5f;
            float xf = floorf(x), yf = floorf(y);
            float lx = x - xf, ly = y - yf;
            int x0 = (int)xf, y0 = (int)yf;
            float aw = lv[l * 4 + p] * inv;
            #pragma unroll
            for (int dy = 0; dy < 2; dy++) {
                #pragma unroll
                for (int dx = 0; dx < 2; dx++) {
                    int yi = y0 + dy, xi = x0 + dx;
                    if (yi < 0 || yi >= H_ || xi < 0 || xi >= W_) continue;
                    float wgt = (dy ? ly : 1.f - ly) * (dx ? lx : 1.f - lx);
                    acc += aw * wgt * vb[(size_t)(s0 + yi * W_ + xi) * 256];
                }
            }
        }
    }
    out16[(size_t)row * 256 + h * 32 + c] = f2bf(acc);
}

// ---------------------------------------------------------------- residual + LN
// 1 wave per row (4 rows/block); 4 f32 per lane, shfl reduction
template<int WRITE16>
__global__ __launch_bounds__(256) void resid_ln(
    const float* __restrict__ a, const float* __restrict__ b,
    const float* __restrict__ g, const float* __restrict__ be,
    float* __restrict__ outf, ushort* __restrict__ outh) {
    const int w = threadIdx.x >> 6, lane = threadIdx.x & 63;
    const int row = blockIdx.x * 4 + w;
    const size_t base = (size_t)row * 256 + lane * 4;
    float4 av = *(const float4*)(a + base);
    float4 bv = *(const float4*)(b + base);
    float4 v = {av.x + bv.x, av.y + bv.y, av.z + bv.z, av.w + bv.w};
    float s  = v.x + v.y + v.z + v.w;
    float s2 = v.x * v.x + v.y * v.y + v.z * v.z + v.w * v.w;
    #pragma unroll
    for (int m = 1; m < 64; m <<= 1) { s += __shfl_xor(s, m); s2 += __shfl_xor(s2, m); }
    float mu  = s * (1.f / 256.f);
    float var = s2 * (1.f / 256.f) - mu * mu;
    float rs  = rsqrtf(var + 1e-5f);
    float4 gv  = *(const float4*)(g + lane * 4);
    float4 bev = *(const float4*)(be + lane * 4);
    float4 o;
    o.x = (v.x - mu) * rs * gv.x + bev.x;
    o.y = (v.y - mu) * rs * gv.y + bev.y;
    o.z = (v.z - mu) * rs * gv.z + bev.z;
    o.w = (v.w - mu) * rs * gv.w + bev.w;
    *(float4*)(outf + base) = o;
    if (WRITE16) {
        ushort4 h4;
        h4.x = f2bf(o.x); h4.y = f2bf(o.y); h4.z = f2bf(o.z); h4.w = f2bf(o.w);
        *(ushort4*)(outh + base) = h4;
    }
}

// ---------------------------------------------------------------- launch
extern "C" void kernel_launch(void* const* d_in, const int* in_sizes, int n_in,
                              void* d_out, int out_size, void* d_ws, size_t ws_size,
                              hipStream_t stream) {
    const float* src  = (const float*)d_in[0];
    const float* pos  = (const float*)d_in[1];
    const float* rp   = (const float*)d_in[2];
    const float* Wv   = (const float*)d_in[5];  const float* bv   = (const float*)d_in[6];
    const float* Woff = (const float*)d_in[7];  const float* boff = (const float*)d_in[8];
    const float* Wa   = (const float*)d_in[9];  const float* ba   = (const float*)d_in[10];
    const float* Wo   = (const float*)d_in[11]; const float* bo   = (const float*)d_in[12];
    const float* W1   = (const float*)d_in[13]; const float* b1   = (const float*)d_in[14];
    const float* W2   = (const float*)d_in[15]; const float* b2   = (const float*)d_in[16];
    const float* g1   = (const float*)d_in[17]; const float* be1  = (const float*)d_in[18];
    const float* g2w  = (const float*)d_in[19]; const float* be2  = (const float*)d_in[20];

    char* ws = (char*)d_ws;
    // region map (bytes); total ~247 MB with reuse
    ushort* s16   = (ushort*)(ws + 0);            // 22,282,240
    ushort* q16   = (ushort*)(ws + 22282240);     // 22,282,240
    float*  value = (float*)(ws + 44564480);      // 44,564,480
    float*  offs  = (float*)(ws + 89128960);      // 44,564,480
    float*  alog  = (float*)(ws + 133693440);     // 22,282,240
    ushort* def16 = (ushort*)(ws + 155975680);    // 22,282,240
    ushort* hid16 = (ushort*)(ws + 89128960);     // reuse offs+alog+def16 (89,128,960)
    float*  x     = (float*)(ws + 178257920);     // 44,564,480
    ushort* x16   = (ushort*)(ws + 222822400);    // 22,282,240
    ushort* wts   = (ushort*)(ws + 245104640);    // 1,511,424
    float*  src2  = value;                        // reuse (value dead after deform)
    float*  ff    = (float*)(ws + 0);             // reuse s16+q16

    ushort* WvT   = wts;
    ushort* WoffT = WvT + 65536;
    ushort* WaT   = WoffT + 65536;
    ushort* WoT   = WaT + 32768;
    ushort* W1T   = WoT + 65536;
    ushort* W2T   = W1T + 262144;

    wtrans<<<256,  256, 0, stream>>>(Wv,   WvT,   256, 256);
    wtrans<<<256,  256, 0, stream>>>(Woff, WoffT, 256, 256);
    wtrans<<<128,  256, 0, stream>>>(Wa,   WaT,   256, 128);
    wtrans<<<256,  256, 0, stream>>>(Wo,   WoT,   256, 256);
    wtrans<<<1024, 256, 0, stream>>>(W1,   W1T,   256, 1024);
    wtrans<<<1024, 256, 0, stream>>>(W2,   W2T,   1024, 256);

    addpos_cast<<<2048, 256, 0, stream>>>(src, pos, s16, q16, NROW * CDIM / 4);

    dim3 grid4(NROW / 128, 4), grid2(NROW / 128, 2), grid16(NROW / 128, 16);
    gemm_bf16<0,0><<<grid4,  256, 0, stream>>>(s16,   WvT,   bv,   value, nullptr, 256, 256);
    gemm_bf16<0,0><<<grid4,  256, 0, stream>>>(q16,   WoffT, boff, offs,  nullptr, 256, 256);
    gemm_bf16<0,0><<<grid2,  256, 0, stream>>>(q16,   WaT,   ba,   alog,  nullptr, 256, 128);

    deform_attn<<<NROW, 256, 0, stream>>>(value, offs, alog, rp, def16);

    gemm_bf16<0,0><<<grid4,  256, 0, stream>>>(def16, WoT,   bo,   src2,  nullptr, 256, 256);
    resid_ln<1><<<NROW / 4, 256, 0, stream>>>(src, src2, g1, be1, x, x16);

    gemm_bf16<1,1><<<grid16, 256, 0, stream>>>(x16,   W1T,   b1,   nullptr, hid16, 256, 1024);
    gemm_bf16<0,0><<<grid4,  256, 0, stream>>>(hid16, W2T,   b2,   ff,    nullptr, 1024, 256);
    resid_ln<0><<<NROW / 4, 256, 0, stream>>>(x, ff, g2w, be2, (float*)d_out, nullptr);
}

// Round 3
// 464.055 us; speedup vs baseline: 1.7368x; 1.7368x over previous
//
#include <hip/hip_runtime.h>
#include <hip/hip_bf16.h>

// Problem constants (fixed by setup_inputs)
#define B_    2
#define LQ    21760
#define NROW  (B_*LQ)      // 43520 = 340*128
#define CDIM  256
#define DFF   1024

typedef __attribute__((ext_vector_type(8))) short bf16x8;
typedef __attribute__((ext_vector_type(4))) float f32x4;

static __device__ __forceinline__ ushort f2bf(float f) {
    union { float f; unsigned u; } v; v.f = f;
    unsigned u = v.u;
    return (ushort)((u + 0x7fffu + ((u >> 16) & 1u)) >> 16);
}

// ---------------------------------------------------------------- elementwise
// q = src + pos; emit bf16 copies of src and q
__global__ void addpos_cast(const float* __restrict__ src, const float* __restrict__ pos,
                            ushort* __restrict__ s16, ushort* __restrict__ q16, int n4) {
    int i = blockIdx.x * blockDim.x + threadIdx.x;
    int stride = gridDim.x * blockDim.x;
    const float4* s4 = (const float4*)src;
    const float4* p4 = (const float4*)pos;
    for (; i < n4; i += stride) {
        float4 s = s4[i], p = p4[i];
        ushort4 a, b;
        a.x = f2bf(s.x); a.y = f2bf(s.y); a.z = f2bf(s.z); a.w = f2bf(s.w);
        b.x = f2bf(s.x + p.x); b.y = f2bf(s.y + p.y);
        b.z = f2bf(s.z + p.z); b.w = f2bf(s.w + p.w);
        ((ushort4*)s16)[i] = a;
        ((ushort4*)q16)[i] = b;
    }
}

// Wt[n*K+k] = bf16(W[k*N+n])   (tiny, one-off)
__global__ void wtrans(const float* __restrict__ W, ushort* __restrict__ Wt, int K, int N) {
    int i = blockIdx.x * blockDim.x + threadIdx.x;
    int total = K * N;
    for (; i < total; i += gridDim.x * blockDim.x) {
        int n = i / K, k = i - n * K;
        Wt[i] = f2bf(W[(size_t)k * N + n]);
    }
}

// ---------------------------------------------------------------- GEMM
// C[M][N] = A[M][K] * B[K][N] (+bias, opt relu), A bf16 row-major, Bt = B^T bf16 [N][K]
// Block tile 128x64, 4 waves (2x2), per-wave 64x32 via 4x2 16x16x32 MFMA frags.
template<int RELU, int OUTBF16>
__global__ __launch_bounds__(256) void gemm_bf16(
    const ushort* __restrict__ A, const ushort* __restrict__ Bt,
    const float* __restrict__ bias,
    float* __restrict__ Cf, ushort* __restrict__ Ch, int K, int N) {
    __shared__ __align__(16) ushort As[128][40];  // +8 pad: 80B row stride -> 2-way (free)
    __shared__ __align__(16) ushort Bs[64][40];
    const int tid  = threadIdx.x;
    const int bm   = blockIdx.x * 128;
    const int bn   = blockIdx.y * 64;
    const int w    = tid >> 6, lane = tid & 63;
    const int wm   = (w >> 1) * 64, wn = (w & 1) * 32;
    const int lr   = lane & 15, lk = lane >> 4;
    const int ar   = tid >> 2, ac = (tid & 3) * 8;   // staging coords

    f32x4 acc[4][2] = {};

    for (int k0 = 0; k0 < K; k0 += 32) {
        *(uint4*)&As[ar][ac]      = *(const uint4*)&A[(size_t)(bm + ar) * K + k0 + ac];
        *(uint4*)&As[ar + 64][ac] = *(const uint4*)&A[(size_t)(bm + ar + 64) * K + k0 + ac];
        *(uint4*)&Bs[ar][ac]      = *(const uint4*)&Bt[(size_t)(bn + ar) * K + k0 + ac];
        __syncthreads();
        bf16x8 af[4], bfr[2];
        #pragma unroll
        for (int m = 0; m < 4; m++) af[m]  = *(const bf16x8*)&As[wm + m * 16 + lr][lk * 8];
        #pragma unroll
        for (int n = 0; n < 2; n++) bfr[n] = *(const bf16x8*)&Bs[wn + n * 16 + lr][lk * 8];
        #pragma unroll
        for (int m = 0; m < 4; m++)
            #pragma unroll
            for (int n = 0; n < 2; n++)
                acc[m][n] = __builtin_amdgcn_mfma_f32_16x16x32_bf16(af[m], bfr[n], acc[m][n], 0, 0, 0);
        __syncthreads();
    }
    // Epilogue. D: col = lane&15, row = (lane>>4)*4 + i
    #pragma unroll
    for (int m = 0; m < 4; m++) {
        int row = bm + wm + m * 16 + lk * 4;
        #pragma unroll
        for (int n = 0; n < 2; n++) {
            int col = bn + wn + n * 16 + lr;
            float bb = bias ? bias[col] : 0.f;
            #pragma unroll
            for (int i = 0; i < 4; i++) {
                float v = acc[m][n][i] + bb;
                if (RELU) v = v > 0.f ? v : 0.f;
                if (OUTBF16) Ch[(size_t)(row + i) * N + col] = f2bf(v);
                else         Cf[(size_t)(row + i) * N + col] = v;
            }
        }
    }
}

// ---------------------------------------------------------------- deform attn
// 1 wave per (b,query) row; 4 rows per block.
// lane = h*8 + c4 : head h in [0,8), c4 in [0,8) covers channels [c4*4, c4*4+4)
__global__ __launch_bounds__(256) void deform_attn(
    const float* __restrict__ value,   // [NROW][256]
    const float* __restrict__ offs,    // [NROW][256] = [NH][NL][NP][2]
    const float* __restrict__ alog,    // [NROW][128] = [NH][16]
    const float* __restrict__ rp,      // [NROW][4][2]
    ushort* __restrict__ out16) {      // [NROW][256] bf16
    const int wid  = threadIdx.x >> 6;
    const int row  = blockIdx.x * 4 + wid;
    const int b    = row / LQ;
    const int lane = threadIdx.x & 63;
    const int h    = lane >> 3, c4 = lane & 7;

    // softmax over 16 logits for head h (duplicated across the 8 c4 lanes)
    const float4* lg4 = (const float4*)(alog + (size_t)row * 128 + h * 16);
    float lv[16];
    #pragma unroll
    for (int j = 0; j < 4; j++) {
        float4 v = lg4[j];
        lv[4*j+0] = v.x; lv[4*j+1] = v.y; lv[4*j+2] = v.z; lv[4*j+3] = v.w;
    }
    float mx = lv[0];
    #pragma unroll
    for (int j = 1; j < 16; j++) mx = fmaxf(mx, lv[j]);
    float sum = 0.f;
    #pragma unroll
    for (int j = 0; j < 16; j++) { lv[j] = __expf(lv[j] - mx); sum += lv[j]; }
    const float inv = 1.f / sum;

    const float* of  = offs + (size_t)row * 256 + h * 32;
    const float* rpr = rp + (size_t)row * 8;
    const float4* vb = (const float4*)(value + (size_t)b * LQ * 256 + h * 32 + c4 * 4);
    // vb stride per pixel: 64 float4

    const int Hs[4] = {128, 64, 32, 16};
    const int st[4] = {0, 16384, 20480, 21504};

    f32x4 acc = {0.f, 0.f, 0.f, 0.f};
    #pragma unroll
    for (int l = 0; l < 4; l++) {
        const int H_ = Hs[l], W_ = Hs[l], s0 = st[l];
        const float fW = (float)W_, fH = (float)H_;
        float rx = rpr[l * 2], ry = rpr[l * 2 + 1];
        #pragma unroll
        for (int p = 0; p < 4; p++) {
            float2 o = *(const float2*)&of[(l * 4 + p) * 2];
            float x = rx * fW + o.x - 0.5f;
            float y = ry * fH + o.y - 0.5f;
            float xf = floorf(x), yf = floorf(y);
            float lx = x - xf, ly = y - yf;
            int x0 = (int)xf, y0 = (int)yf;
            float aw = lv[l * 4 + p] * inv;
            #pragma unroll
            for (int dy = 0; dy < 2; dy++) {
                #pragma unroll
                for (int dx = 0; dx < 2; dx++) {
                    int yi = y0 + dy, xi = x0 + dx;
                    bool ok = ((unsigned)yi < (unsigned)H_) & ((unsigned)xi < (unsigned)W_);
                    int yc = min(max(yi, 0), H_ - 1);
                    int xc = min(max(xi, 0), W_ - 1);
                    float wgt = (dy ? ly : 1.f - ly) * (dx ? lx : 1.f - lx) * aw;
                    wgt = ok ? wgt : 0.f;
                    f32x4 v = *(const f32x4*)&vb[(size_t)(s0 + yc * W_ + xc) * 64];
                    acc += wgt * v;
                }
            }
        }
    }
    ushort4 o4;
    o4.x = f2bf(acc[0]); o4.y = f2bf(acc[1]);
    o4.z = f2bf(acc[2]); o4.w = f2bf(acc[3]);
    *(ushort4*)(out16 + (size_t)row * 256 + h * 32 + c4 * 4) = o4;
}

// ---------------------------------------------------------------- residual + LN
// 1 wave per row (4 rows/block); 4 f32 per lane, shfl reduction
template<int WRITE16>
__global__ __launch_bounds__(256) void resid_ln(
    const float* __restrict__ a, const float* __restrict__ b,
    const float* __restrict__ g, const float* __restrict__ be,
    float* __restrict__ outf, ushort* __restrict__ outh) {
    const int w = threadIdx.x >> 6, lane = threadIdx.x & 63;
    const int row = blockIdx.x * 4 + w;
    const size_t base = (size_t)row * 256 + lane * 4;
    float4 av = *(const float4*)(a + base);
    float4 bv = *(const float4*)(b + base);
    float4 v = {av.x + bv.x, av.y + bv.y, av.z + bv.z, av.w + bv.w};
    float s  = v.x + v.y + v.z + v.w;
    float s2 = v.x * v.x + v.y * v.y + v.z * v.z + v.w * v.w;
    #pragma unroll
    for (int m = 1; m < 64; m <<= 1) { s += __shfl_xor(s, m); s2 += __shfl_xor(s2, m); }
    float mu  = s * (1.f / 256.f);
    float var = s2 * (1.f / 256.f) - mu * mu;
    float rs  = rsqrtf(var + 1e-5f);
    float4 gv  = *(const float4*)(g + lane * 4);
    float4 bev = *(const float4*)(be + lane * 4);
    float4 o;
    o.x = (v.x - mu) * rs * gv.x + bev.x;
    o.y = (v.y - mu) * rs * gv.y + bev.y;
    o.z = (v.z - mu) * rs * gv.z + bev.z;
    o.w = (v.w - mu) * rs * gv.w + bev.w;
    *(float4*)(outf + base) = o;
    if (WRITE16) {
        ushort4 h4;
        h4.x = f2bf(o.x); h4.y = f2bf(o.y); h4.z = f2bf(o.z); h4.w = f2bf(o.w);
        *(ushort4*)(outh + base) = h4;
    }
}

// ---------------------------------------------------------------- launch
extern "C" void kernel_launch(void* const* d_in, const int* in_sizes, int n_in,
                              void* d_out, int out_size, void* d_ws, size_t ws_size,
                              hipStream_t stream) {
    const float* src  = (const float*)d_in[0];
    const float* pos  = (const float*)d_in[1];
    const float* rp   = (const float*)d_in[2];
    const float* Wv   = (const float*)d_in[5];  const float* bv   = (const float*)d_in[6];
    const float* Woff = (const float*)d_in[7];  const float* boff = (const float*)d_in[8];
    const float* Wa   = (const float*)d_in[9];  const float* ba   = (const float*)d_in[10];
    const float* Wo   = (const float*)d_in[11]; const float* bo   = (const float*)d_in[12];
    const float* W1   = (const float*)d_in[13]; const float* b1   = (const float*)d_in[14];
    const float* W2   = (const float*)d_in[15]; const float* b2   = (const float*)d_in[16];
    const float* g1   = (const float*)d_in[17]; const float* be1  = (const float*)d_in[18];
    const float* g2w  = (const float*)d_in[19]; const float* be2  = (const float*)d_in[20];

    char* ws = (char*)d_ws;
    // region map (bytes); total ~247 MB with reuse
    ushort* s16   = (ushort*)(ws + 0);            // 22,282,240
    ushort* q16   = (ushort*)(ws + 22282240);     // 22,282,240
    float*  value = (float*)(ws + 44564480);      // 44,564,480
    float*  offs  = (float*)(ws + 89128960);      // 44,564,480
    float*  alog  = (float*)(ws + 133693440);     // 22,282,240
    ushort* def16 = (ushort*)(ws + 155975680);    // 22,282,240
    ushort* hid16 = (ushort*)(ws + 89128960);     // reuse offs+alog+def16 (89,128,960)
    float*  x     = (float*)(ws + 178257920);     // 44,564,480
    ushort* x16   = (ushort*)(ws + 222822400);    // 22,282,240
    ushort* wts   = (ushort*)(ws + 245104640);    // 1,511,424
    float*  src2  = value;                        // reuse (value dead after deform)
    float*  ff    = (float*)(ws + 0);             // reuse s16+q16

    ushort* WvT   = wts;
    ushort* WoffT = WvT + 65536;
    ushort* WaT   = WoffT + 65536;
    ushort* WoT   = WaT + 32768;
    ushort* W1T   = WoT + 65536;
    ushort* W2T   = W1T + 262144;

    wtrans<<<256,  256, 0, stream>>>(Wv,   WvT,   256, 256);
    wtrans<<<256,  256, 0, stream>>>(Woff, WoffT, 256, 256);
    wtrans<<<128,  256, 0, stream>>>(Wa,   WaT,   256, 128);
    wtrans<<<256,  256, 0, stream>>>(Wo,   WoT,   256, 256);
    wtrans<<<1024, 256, 0, stream>>>(W1,   W1T,   256, 1024);
    wtrans<<<1024, 256, 0, stream>>>(W2,   W2T,   1024, 256);

    addpos_cast<<<2048, 256, 0, stream>>>(src, pos, s16, q16, NROW * CDIM / 4);

    dim3 grid4(NROW / 128, 4), grid2(NROW / 128, 2), grid16(NROW / 128, 16);
    gemm_bf16<0,0><<<grid4,  256, 0, stream>>>(s16,   WvT,   bv,   value, nullptr, 256, 256);
    gemm_bf16<0,0><<<grid4,  256, 0, stream>>>(q16,   WoffT, boff, offs,  nullptr, 256, 256);
    gemm_bf16<0,0><<<grid2,  256, 0, stream>>>(q16,   WaT,   ba,   alog,  nullptr, 256, 128);

    deform_attn<<<NROW / 4, 256, 0, stream>>>(value, offs, alog, rp, def16);

    gemm_bf16<0,0><<<grid4,  256, 0, stream>>>(def16, WoT,   bo,   src2,  nullptr, 256, 256);
    resid_ln<1><<<NROW / 4, 256, 0, stream>>>(src, src2, g1, be1, x, x16);

    gemm_bf16<1,1><<<grid16, 256, 0, stream>>>(x16,   W1T,   b1,   nullptr, hid16, 256, 1024);
    gemm_bf16<0,0><<<grid4,  256, 0, stream>>>(hid16, W2T,   b2,   ff,    nullptr, 1024, 256);
    resid_ln<0><<<NROW / 4, 256, 0, stream>>>(x, ff, g2w, be2, (float*)d_out, nullptr);
}

// Round 4
// 384.850 us; speedup vs baseline: 2.0943x; 1.2058x over previous
//
#include <hip/hip_runtime.h>
#include <hip/hip_bf16.h>

// Problem constants (fixed by setup_inputs)
#define B_    2
#define LQ    21760
#define NROW  (B_*LQ)      // 43520 = 340*128
#define CDIM  256
#define DFF   1024

typedef __attribute__((ext_vector_type(8))) short bf16x8;
typedef __attribute__((ext_vector_type(4))) float f32x4;

static __device__ __forceinline__ ushort f2bf(float f) {
    union { float f; unsigned u; } v; v.f = f;
    unsigned u = v.u;
    return (ushort)((u + 0x7fffu + ((u >> 16) & 1u)) >> 16);
}
static __device__ __forceinline__ float u2f(unsigned u) {
    union { unsigned u; float f; } v; v.u = u; return v.f;
}

// ---------------------------------------------------------------- elementwise
// q = src + pos; emit bf16 copies of src and q
__global__ void addpos_cast(const float* __restrict__ src, const float* __restrict__ pos,
                            ushort* __restrict__ s16, ushort* __restrict__ q16, int n4) {
    int i = blockIdx.x * blockDim.x + threadIdx.x;
    int stride = gridDim.x * blockDim.x;
    const float4* s4 = (const float4*)src;
    const float4* p4 = (const float4*)pos;
    for (; i < n4; i += stride) {
        float4 s = s4[i], p = p4[i];
        ushort4 a, b;
        a.x = f2bf(s.x); a.y = f2bf(s.y); a.z = f2bf(s.z); a.w = f2bf(s.w);
        b.x = f2bf(s.x + p.x); b.y = f2bf(s.y + p.y);
        b.z = f2bf(s.z + p.z); b.w = f2bf(s.w + p.w);
        ((ushort4*)s16)[i] = a;
        ((ushort4*)q16)[i] = b;
    }
}

// All six weight transposes in one launch. Wt[n*K+k] = bf16(W[k*N+n])
static __device__ __forceinline__ void wt_one(const float* W, ushort* Wt, int K, int N, int i) {
    int n = i / K, k = i - n * K;
    Wt[i] = f2bf(W[(size_t)k * N + n]);
}
__global__ void wtrans_all(const float* Wv, const float* Woff, const float* Wa,
                           const float* Wo, const float* W1, const float* W2,
                           ushort* WvT, ushort* WoffT, ushort* WaT,
                           ushort* WoT, ushort* W1T, ushort* W2T) {
    int gid = blockIdx.x * 256 + threadIdx.x;  // total 753664 = 2944 * 256
    if      (gid < 65536)  wt_one(Wv,   WvT,   256, 256,  gid);
    else if (gid < 131072) wt_one(Woff, WoffT, 256, 256,  gid - 65536);
    else if (gid < 163840) wt_one(Wa,   WaT,   256, 128,  gid - 131072);
    else if (gid < 229376) wt_one(Wo,   WoT,   256, 256,  gid - 163840);
    else if (gid < 491520) wt_one(W1,   W1T,   256, 1024, gid - 229376);
    else                   wt_one(W2,   W2T,   1024, 256, gid - 491520);
}

// ---------------------------------------------------------------- GEMM
// C[M][N] = A[M][K] * B[K][N] (+bias, opt relu), A bf16 row-major, Bt = B^T bf16 [N][K]
// Block tile 128x64, BK=64, 4 waves (2x2), per-wave 64x32 via 4x2 16x16x32 MFMA frags.
template<int RELU, int OUTBF16>
__global__ __launch_bounds__(256) void gemm_bf16(
    const ushort* __restrict__ A, const ushort* __restrict__ Bt,
    const float* __restrict__ bias,
    float* __restrict__ Cf, ushort* __restrict__ Ch, int K, int N) {
    __shared__ __align__(16) ushort As[128][72];  // +8 pad: 144B stride -> 2-way (free)
    __shared__ __align__(16) ushort Bs[64][72];
    const int tid  = threadIdx.x;
    const int bm   = blockIdx.x * 128;
    const int bn   = blockIdx.y * 64;
    const int w    = tid >> 6, lane = tid & 63;
    const int wm   = (w >> 1) * 64, wn = (w & 1) * 32;
    const int lr   = lane & 15, lk = lane >> 4;
    const int ar   = tid >> 3, ac = (tid & 7) * 8;   // staging: 32 rows x 8 chunks per pass

    f32x4 acc[4][2] = {};

    for (int k0 = 0; k0 < K; k0 += 64) {
        #pragma unroll
        for (int c = 0; c < 4; c++)
            *(uint4*)&As[ar + c * 32][ac] = *(const uint4*)&A[(size_t)(bm + ar + c * 32) * K + k0 + ac];
        #pragma unroll
        for (int c = 0; c < 2; c++)
            *(uint4*)&Bs[ar + c * 32][ac] = *(const uint4*)&Bt[(size_t)(bn + ar + c * 32) * K + k0 + ac];
        __syncthreads();
        #pragma unroll
        for (int ks = 0; ks < 2; ks++) {
            bf16x8 af[4], bfr[2];
            #pragma unroll
            for (int m = 0; m < 4; m++) af[m]  = *(const bf16x8*)&As[wm + m * 16 + lr][ks * 32 + lk * 8];
            #pragma unroll
            for (int n = 0; n < 2; n++) bfr[n] = *(const bf16x8*)&Bs[wn + n * 16 + lr][ks * 32 + lk * 8];
            #pragma unroll
            for (int m = 0; m < 4; m++)
                #pragma unroll
                for (int n = 0; n < 2; n++)
                    acc[m][n] = __builtin_amdgcn_mfma_f32_16x16x32_bf16(af[m], bfr[n], acc[m][n], 0, 0, 0);
        }
        __syncthreads();
    }
    // Epilogue. D: col = lane&15, row = (lane>>4)*4 + i
    #pragma unroll
    for (int m = 0; m < 4; m++) {
        int row = bm + wm + m * 16 + lk * 4;
        #pragma unroll
        for (int n = 0; n < 2; n++) {
            int col = bn + wn + n * 16 + lr;
            float bb = bias ? bias[col] : 0.f;
            #pragma unroll
            for (int i = 0; i < 4; i++) {
                float v = acc[m][n][i] + bb;
                if (RELU) v = v > 0.f ? v : 0.f;
                if (OUTBF16) Ch[(size_t)(row + i) * N + col] = f2bf(v);
                else         Cf[(size_t)(row + i) * N + col] = v;
            }
        }
    }
}

// ---------------------------------------------------------------- deform attn
// 1 wave per (b,query) row; 4 rows per block.
// lane = h*8 + c4 : head h in [0,8), c4 in [0,8) covers channels [c4*4, c4*4+4)
// value is bf16 [B][LQ][256]; each corner gather is uint2 (4 bf16 = 8B/lane)
__global__ __launch_bounds__(256) void deform_attn(
    const ushort* __restrict__ val16,  // [NROW][256] bf16
    const float* __restrict__ offs,    // [NROW][256] = [NH][NL][NP][2]
    const float* __restrict__ alog,    // [NROW][128] = [NH][16]
    const float* __restrict__ rp,      // [NROW][4][2]
    ushort* __restrict__ out16) {      // [NROW][256] bf16
    const int wid  = threadIdx.x >> 6;
    const int row  = blockIdx.x * 4 + wid;
    const int b    = row / LQ;
    const int lane = threadIdx.x & 63;
    const int h    = lane >> 3, c4 = lane & 7;

    // softmax over 16 logits for head h (duplicated across the 8 c4 lanes)
    const float4* lg4 = (const float4*)(alog + (size_t)row * 128 + h * 16);
    float lv[16];
    #pragma unroll
    for (int j = 0; j < 4; j++) {
        float4 v = lg4[j];
        lv[4*j+0] = v.x; lv[4*j+1] = v.y; lv[4*j+2] = v.z; lv[4*j+3] = v.w;
    }
    float mx = lv[0];
    #pragma unroll
    for (int j = 1; j < 16; j++) mx = fmaxf(mx, lv[j]);
    float sum = 0.f;
    #pragma unroll
    for (int j = 0; j < 16; j++) { lv[j] = __expf(lv[j] - mx); sum += lv[j]; }
    const float inv = 1.f / sum;

    const float* of  = offs + (size_t)row * 256 + h * 32;
    const float* rpr = rp + (size_t)row * 8;
    const ushort* vb = val16 + (size_t)b * LQ * 256 + h * 32 + c4 * 4;

    const int Hs[4] = {128, 64, 32, 16};
    const int st[4] = {0, 16384, 20480, 21504};

    float a0 = 0.f, a1 = 0.f, a2 = 0.f, a3 = 0.f;
    #pragma unroll
    for (int l = 0; l < 4; l++) {
        const int H_ = Hs[l], W_ = Hs[l], s0 = st[l];
        const float fW = (float)W_, fH = (float)H_;
        float rx = rpr[l * 2], ry = rpr[l * 2 + 1];
        #pragma unroll
        for (int p = 0; p < 4; p++) {
            float2 o = *(const float2*)&of[(l * 4 + p) * 2];
            float x = rx * fW + o.x - 0.5f;
            float y = ry * fH + o.y - 0.5f;
            float xf = floorf(x), yf = floorf(y);
            float lx = x - xf, ly = y - yf;
            int x0 = (int)xf, y0 = (int)yf;
            float aw = lv[l * 4 + p] * inv;
            #pragma unroll
            for (int dy = 0; dy < 2; dy++) {
                #pragma unroll
                for (int dx = 0; dx < 2; dx++) {
                    int yi = y0 + dy, xi = x0 + dx;
                    bool ok = ((unsigned)yi < (unsigned)H_) & ((unsigned)xi < (unsigned)W_);
                    int yc = min(max(yi, 0), H_ - 1);
                    int xc = min(max(xi, 0), W_ - 1);
                    float wgt = (dy ? ly : 1.f - ly) * (dx ? lx : 1.f - lx) * aw;
                    wgt = ok ? wgt : 0.f;
                    uint2 uu = *(const uint2*)&vb[(size_t)(s0 + yc * W_ + xc) * 256];
                    a0 += wgt * u2f(uu.x << 16);
                    a1 += wgt * u2f(uu.x & 0xffff0000u);
                    a2 += wgt * u2f(uu.y << 16);
                    a3 += wgt * u2f(uu.y & 0xffff0000u);
                }
            }
        }
    }
    ushort4 o4;
    o4.x = f2bf(a0); o4.y = f2bf(a1);
    o4.z = f2bf(a2); o4.w = f2bf(a3);
    *(ushort4*)(out16 + (size_t)row * 256 + h * 32 + c4 * 4) = o4;
}

// ---------------------------------------------------------------- residual + LN
// 1 wave per row (4 rows/block); 4 f32 per lane, shfl reduction
template<int WRITE16>
__global__ __launch_bounds__(256) void resid_ln(
    const float* __restrict__ a, const float* __restrict__ b,
    const float* __restrict__ g, const float* __restrict__ be,
    float* __restrict__ outf, ushort* __restrict__ outh) {
    const int w = threadIdx.x >> 6, lane = threadIdx.x & 63;
    const int row = blockIdx.x * 4 + w;
    const size_t base = (size_t)row * 256 + lane * 4;
    float4 av = *(const float4*)(a + base);
    float4 bv = *(const float4*)(b + base);
    float4 v = {av.x + bv.x, av.y + bv.y, av.z + bv.z, av.w + bv.w};
    float s  = v.x + v.y + v.z + v.w;
    float s2 = v.x * v.x + v.y * v.y + v.z * v.z + v.w * v.w;
    #pragma unroll
    for (int m = 1; m < 64; m <<= 1) { s += __shfl_xor(s, m); s2 += __shfl_xor(s2, m); }
    float mu  = s * (1.f / 256.f);
    float var = s2 * (1.f / 256.f) - mu * mu;
    float rs  = rsqrtf(var + 1e-5f);
    float4 gv  = *(const float4*)(g + lane * 4);
    float4 bev = *(const float4*)(be + lane * 4);
    float4 o;
    o.x = (v.x - mu) * rs * gv.x + bev.x;
    o.y = (v.y - mu) * rs * gv.y + bev.y;
    o.z = (v.z - mu) * rs * gv.z + bev.z;
    o.w = (v.w - mu) * rs * gv.w + bev.w;
    *(float4*)(outf + base) = o;
    if (WRITE16) {
        ushort4 h4;
        h4.x = f2bf(o.x); h4.y = f2bf(o.y); h4.z = f2bf(o.z); h4.w = f2bf(o.w);
        *(ushort4*)(outh + base) = h4;
    }
}

// ---------------------------------------------------------------- launch
extern "C" void kernel_launch(void* const* d_in, const int* in_sizes, int n_in,
                              void* d_out, int out_size, void* d_ws, size_t ws_size,
                              hipStream_t stream) {
    const float* src  = (const float*)d_in[0];
    const float* pos  = (const float*)d_in[1];
    const float* rp   = (const float*)d_in[2];
    const float* Wv   = (const float*)d_in[5];  const float* bv   = (const float*)d_in[6];
    const float* Woff = (const float*)d_in[7];  const float* boff = (const float*)d_in[8];
    const float* Wa   = (const float*)d_in[9];  const float* ba   = (const float*)d_in[10];
    const float* Wo   = (const float*)d_in[11]; const float* bo   = (const float*)d_in[12];
    const float* W1   = (const float*)d_in[13]; const float* b1   = (const float*)d_in[14];
    const float* W2   = (const float*)d_in[15]; const float* b2   = (const float*)d_in[16];
    const float* g1   = (const float*)d_in[17]; const float* be1  = (const float*)d_in[18];
    const float* g2w  = (const float*)d_in[19]; const float* be2  = (const float*)d_in[20];

    char* ws = (char*)d_ws;
    // region map (bytes), ~224 MB total with reuse
    ushort* s16   = (ushort*)(ws + 0);            // 22,282,240
    ushort* q16   = (ushort*)(ws + 22282240);     // 22,282,240
    ushort* val16 = (ushort*)(ws + 44564480);     // 22,282,240 (bf16 value)
    float*  offs  = (float*)(ws + 66846720);      // 44,564,480
    float*  alog  = (float*)(ws + 111411200);     // 22,282,240
    ushort* def16 = (ushort*)(ws + 133693440);    // 22,282,240
    float*  x     = (float*)(ws + 155975680);     // 44,564,480
    ushort* x16   = (ushort*)(ws + 200540160);    // 22,282,240
    ushort* wts   = (ushort*)(ws + 222822400);    // 1,507,328
    float*  src2  = (float*)(ws + 0);             // reuse s16+q16 (dead after q GEMMs)
    ushort* hid16 = (ushort*)(ws + 44564480);     // reuse val16+offs+alog (89,128,960)
    float*  ff    = (float*)(ws + 0);             // reuse src2 (dead after LN1)

    ushort* WvT   = wts;
    ushort* WoffT = WvT + 65536;
    ushort* WaT   = WoffT + 65536;
    ushort* WoT   = WaT + 32768;
    ushort* W1T   = WoT + 65536;
    ushort* W2T   = W1T + 262144;

    wtrans_all<<<2944, 256, 0, stream>>>(Wv, Woff, Wa, Wo, W1, W2,
                                         WvT, WoffT, WaT, WoT, W1T, W2T);

    addpos_cast<<<2048, 256, 0, stream>>>(src, pos, s16, q16, NROW * CDIM / 4);

    dim3 grid4(NROW / 128, 4), grid2(NROW / 128, 2), grid16(NROW / 128, 16);
    gemm_bf16<0,1><<<grid4,  256, 0, stream>>>(s16,   WvT,   bv,   nullptr, val16, 256, 256);
    gemm_bf16<0,0><<<grid4,  256, 0, stream>>>(q16,   WoffT, boff, offs,  nullptr, 256, 256);
    gemm_bf16<0,0><<<grid2,  256, 0, stream>>>(q16,   WaT,   ba,   alog,  nullptr, 256, 128);

    deform_attn<<<NROW / 4, 256, 0, stream>>>(val16, offs, alog, rp, def16);

    gemm_bf16<0,0><<<grid4,  256, 0, stream>>>(def16, WoT,   bo,   src2,  nullptr, 256, 256);
    resid_ln<1><<<NROW / 4, 256, 0, stream>>>(src, src2, g1, be1, x, x16);

    gemm_bf16<1,1><<<grid16, 256, 0, stream>>>(x16,   W1T,   b1,   nullptr, hid16, 256, 1024);
    gemm_bf16<0,0><<<grid4,  256, 0, stream>>>(hid16, W2T,   b2,   ff,    nullptr, 1024, 256);
    resid_ln<0><<<NROW / 4, 256, 0, stream>>>(x, ff, g2w, be2, (float*)d_out, nullptr);
}

// Round 5
// 361.758 us; speedup vs baseline: 2.2280x; 1.0638x over previous
//
#include <hip/hip_runtime.h>
#include <hip/hip_bf16.h>

// Problem constants (fixed by setup_inputs)
#define B_    2
#define LQ    21760
#define NROW  (B_*LQ)      // 43520 = 340*128
#define CDIM  256
#define DFF   1024

typedef __attribute__((ext_vector_type(8))) short bf16x8;
typedef __attribute__((ext_vector_type(4))) float f32x4;

static __device__ __forceinline__ ushort f2bf(float f) {
    union { float f; unsigned u; } v; v.f = f;
    unsigned u = v.u;
    return (ushort)((u + 0x7fffu + ((u >> 16) & 1u)) >> 16);
}
static __device__ __forceinline__ float u2f(unsigned u) {
    union { unsigned u; float f; } v; v.u = u; return v.f;
}

// ---------------------------------------------------------------- elementwise
// q = src + pos; emit bf16 copies of src and q
__global__ void addpos_cast(const float* __restrict__ src, const float* __restrict__ pos,
                            ushort* __restrict__ s16, ushort* __restrict__ q16, int n4) {
    int i = blockIdx.x * blockDim.x + threadIdx.x;
    int stride = gridDim.x * blockDim.x;
    const float4* s4 = (const float4*)src;
    const float4* p4 = (const float4*)pos;
    for (; i < n4; i += stride) {
        float4 s = s4[i], p = p4[i];
        ushort4 a, b;
        a.x = f2bf(s.x); a.y = f2bf(s.y); a.z = f2bf(s.z); a.w = f2bf(s.w);
        b.x = f2bf(s.x + p.x); b.y = f2bf(s.y + p.y);
        b.z = f2bf(s.z + p.z); b.w = f2bf(s.w + p.w);
        ((ushort4*)s16)[i] = a;
        ((ushort4*)q16)[i] = b;
    }
}

// All weight transposes + concat bias in one launch.
static __device__ __forceinline__ void wt_one(const float* W, ushort* Wt, int K, int N, int i) {
    int n = i / K, k = i - n * K;
    Wt[i] = f2bf(W[(size_t)k * N + n]);
}
__global__ void wtrans_all(const float* Wv, const float* Woff, const float* Wa,
                           const float* Wo, const float* W1, const float* W2,
                           const float* boff, const float* ba,
                           ushort* WvT, ushort* WqT, ushort* WoT,
                           ushort* W1T, ushort* W2T, float* bq) {
    int gid = blockIdx.x * 256 + threadIdx.x;   // 2946*256 = 754176 >= 754048
    if (gid < 65536)  { wt_one(Wv, WvT, 256, 256, gid); return; }
    if (gid < 163840) {                // WqT[384][256]: Woff cols 0..255, Wa cols 256..383
        int i = gid - 65536;
        int n = i >> 8, k = i & 255;
        float v = (n < 256) ? Woff[(size_t)k * 256 + n] : Wa[(size_t)k * 128 + (n - 256)];
        WqT[i] = f2bf(v);
        return;
    }
    if (gid < 229376) { wt_one(Wo, WoT, 256, 256,  gid - 163840); return; }
    if (gid < 491520) { wt_one(W1, W1T, 256, 1024, gid - 229376); return; }
    if (gid < 753664) { wt_one(W2, W2T, 1024, 256, gid - 491520); return; }
    if (gid < 754048) {
        int i = gid - 753664;
        bq[i] = (i < 256) ? boff[i] : ba[i - 256];
    }
}

// ---------------------------------------------------------------- GEMM
// C[M][N] = A[M][K] * B[K][N] (+bias, opt relu), A bf16 row-major, Bt = B^T bf16 [N][K]
// Block tile 128x64, BK=64, 4 waves (2x2), per-wave 64x32 via 4x2 16x16x32 MFMA frags.
template<int RELU, int OUTBF16>
__global__ __launch_bounds__(256) void gemm_bf16(
    const ushort* __restrict__ A, const ushort* __restrict__ Bt,
    const float* __restrict__ bias,
    float* __restrict__ Cf, ushort* __restrict__ Ch, int K, int N) {
    __shared__ __align__(16) ushort As[128][72];  // +8 pad: 144B stride -> 2-way (free)
    __shared__ __align__(16) ushort Bs[64][72];
    const int tid  = threadIdx.x;
    const int bm   = blockIdx.x * 128;
    const int bn   = blockIdx.y * 64;
    const int w    = tid >> 6, lane = tid & 63;
    const int wm   = (w >> 1) * 64, wn = (w & 1) * 32;
    const int lr   = lane & 15, lk = lane >> 4;
    const int ar   = tid >> 3, ac = (tid & 7) * 8;   // staging: 32 rows x 8 chunks per pass

    f32x4 acc[4][2] = {};

    for (int k0 = 0; k0 < K; k0 += 64) {
        #pragma unroll
        for (int c = 0; c < 4; c++)
            *(uint4*)&As[ar + c * 32][ac] = *(const uint4*)&A[(size_t)(bm + ar + c * 32) * K + k0 + ac];
        #pragma unroll
        for (int c = 0; c < 2; c++)
            *(uint4*)&Bs[ar + c * 32][ac] = *(const uint4*)&Bt[(size_t)(bn + ar + c * 32) * K + k0 + ac];
        __syncthreads();
        #pragma unroll
        for (int ks = 0; ks < 2; ks++) {
            bf16x8 af[4], bfr[2];
            #pragma unroll
            for (int m = 0; m < 4; m++) af[m]  = *(const bf16x8*)&As[wm + m * 16 + lr][ks * 32 + lk * 8];
            #pragma unroll
            for (int n = 0; n < 2; n++) bfr[n] = *(const bf16x8*)&Bs[wn + n * 16 + lr][ks * 32 + lk * 8];
            #pragma unroll
            for (int m = 0; m < 4; m++)
                #pragma unroll
                for (int n = 0; n < 2; n++)
                    acc[m][n] = __builtin_amdgcn_mfma_f32_16x16x32_bf16(af[m], bfr[n], acc[m][n], 0, 0, 0);
        }
        __syncthreads();
    }
    // Epilogue. D: col = lane&15, row = (lane>>4)*4 + i
    #pragma unroll
    for (int m = 0; m < 4; m++) {
        int row = bm + wm + m * 16 + lk * 4;
        #pragma unroll
        for (int n = 0; n < 2; n++) {
            int col = bn + wn + n * 16 + lr;
            float bb = bias ? bias[col] : 0.f;
            #pragma unroll
            for (int i = 0; i < 4; i++) {
                float v = acc[m][n][i] + bb;
                if (RELU) v = v > 0.f ? v : 0.f;
                if (OUTBF16) Ch[(size_t)(row + i) * N + col] = f2bf(v);
                else         Cf[(size_t)(row + i) * N + col] = v;
            }
        }
    }
}

// ---------------------------------------------------------------- deform attn
// 1 wave per (b,query) row; 4 rows per block.
// Phase A: lane = h*8+j computes points {2j,2j+1} of head h -> LDS records {off,wgt}
// Phase B: lane = h*8+c4 gathers 64 corners for channels [c4*4, c4*4+4)
__global__ __launch_bounds__(256) void deform_attn(
    const ushort* __restrict__ val16,  // [B][LQ][256] bf16
    const float* __restrict__ qout,    // [NROW][384]: [0,256)=offs, [256,384)=attn logits
    const float* __restrict__ rp,      // [NROW][4][2]
    ushort* __restrict__ out16) {      // [NROW][256] bf16
    __shared__ uint2 rec[4][8][66];    // 66 = 64 records + 2 pad (head stride 528B)
    const int wid  = threadIdx.x >> 6;
    const int row  = blockIdx.x * 4 + wid;
    const int lane = threadIdx.x & 63;
    const int h    = lane >> 3;
    const int j    = lane & 7;
    const int b    = row / LQ;

    const float* qrow = qout + (size_t)row * 384;

    // ---- phase A: softmax (8-lane group reduce) + 2 points per lane
    float2 lg = *(const float2*)(qrow + 256 + h * 16 + j * 2);
    float m = fmaxf(lg.x, lg.y);
    m = fmaxf(m, __shfl_xor(m, 1, 8));
    m = fmaxf(m, __shfl_xor(m, 2, 8));
    m = fmaxf(m, __shfl_xor(m, 4, 8));
    float e0 = __expf(lg.x - m), e1 = __expf(lg.y - m);
    float s = e0 + e1;
    s += __shfl_xor(s, 1, 8);
    s += __shfl_xor(s, 2, 8);
    s += __shfl_xor(s, 4, 8);
    const float inv = 1.f / s;

    const int L  = j >> 1;              // both points of this lane share a level
    const int Wl = 128 >> L;
    const int s0 = (L == 0) ? 0 : (L == 1) ? 16384 : (L == 2) ? 20480 : 21504;
    const float fW = (float)Wl;
    float2 rr  = *(const float2*)(rp + (size_t)row * 8 + L * 2);
    float4 ofv = *(const float4*)(qrow + h * 32 + j * 4);

    #pragma unroll
    for (int pt = 0; pt < 2; pt++) {
        float ox = pt ? ofv.z : ofv.x;
        float oy = pt ? ofv.w : ofv.y;
        float aw = (pt ? e1 : e0) * inv;
        float x = rr.x * fW + ox - 0.5f;
        float y = rr.y * fW + oy - 0.5f;
        float xf = floorf(x), yf = floorf(y);
        float lx = x - xf, ly = y - yf;
        int x0 = (int)xf, y0 = (int)yf;
        int x1 = x0 + 1, y1 = y0 + 1;
        int x0c = min(max(x0, 0), Wl - 1), x1c = min(max(x1, 0), Wl - 1);
        int y0c = min(max(y0, 0), Wl - 1), y1c = min(max(y1, 0), Wl - 1);
        bool vx0 = (unsigned)x0 < (unsigned)Wl, vx1 = (unsigned)x1 < (unsigned)Wl;
        bool vy0 = (unsigned)y0 < (unsigned)Wl, vy1 = (unsigned)y1 < (unsigned)Wl;
        float wx1 = lx, wx0 = 1.f - lx, wy1 = ly, wy0 = 1.f - ly;
        float w00 = (vy0 & vx0) ? aw * wy0 * wx0 : 0.f;
        float w01 = (vy0 & vx1) ? aw * wy0 * wx1 : 0.f;
        float w10 = (vy1 & vx0) ? aw * wy1 * wx0 : 0.f;
        float w11 = (vy1 & vx1) ? aw * wy1 * wx1 : 0.f;
        unsigned hb = (unsigned)h * 64u;
        unsigned o00 = (unsigned)(s0 + y0c * Wl + x0c) * 512u + hb;
        unsigned o01 = (unsigned)(s0 + y0c * Wl + x1c) * 512u + hb;
        unsigned o10 = (unsigned)(s0 + y1c * Wl + x0c) * 512u + hb;
        unsigned o11 = (unsigned)(s0 + y1c * Wl + x1c) * 512u + hb;
        uint4* dst = (uint4*)&rec[wid][h][(j * 2 + pt) * 4];
        dst[0] = make_uint4(o00, __float_as_uint(w00), o01, __float_as_uint(w01));
        dst[1] = make_uint4(o10, __float_as_uint(w10), o11, __float_as_uint(w11));
    }
    __syncthreads();

    // ---- phase B: gather. c4 = j
    const int bu = __builtin_amdgcn_readfirstlane(b);  // wave-uniform -> SGPR base
    const char* ubase = (const char*)val16 + (size_t)bu * (LQ * 512);
    const unsigned coff = (unsigned)j * 8u;
    const uint2* r = &rec[wid][h][0];
    float a0 = 0.f, a1 = 0.f, a2 = 0.f, a3 = 0.f;
    #pragma unroll 8
    for (int i = 0; i < 64; i++) {
        uint2 rw = r[i];
        float wgt = u2f(rw.y);
        uint2 uu = *(const uint2*)(ubase + (rw.x + coff));
        a0 += wgt * u2f(uu.x << 16);
        a1 += wgt * u2f(uu.x & 0xffff0000u);
        a2 += wgt * u2f(uu.y << 16);
        a3 += wgt * u2f(uu.y & 0xffff0000u);
    }
    ushort4 o4;
    o4.x = f2bf(a0); o4.y = f2bf(a1);
    o4.z = f2bf(a2); o4.w = f2bf(a3);
    *(ushort4*)(out16 + (size_t)row * 256 + h * 32 + j * 4) = o4;
}

// ---------------------------------------------------------------- residual + LN
// 1 wave per row (4 rows/block); 4 f32 per lane, shfl reduction
template<int WRITE16>
__global__ __launch_bounds__(256) void resid_ln(
    const float* __restrict__ a, const float* __restrict__ b,
    const float* __restrict__ g, const float* __restrict__ be,
    float* __restrict__ outf, ushort* __restrict__ outh) {
    const int w = threadIdx.x >> 6, lane = threadIdx.x & 63;
    const int row = blockIdx.x * 4 + w;
    const size_t base = (size_t)row * 256 + lane * 4;
    float4 av = *(const float4*)(a + base);
    float4 bv = *(const float4*)(b + base);
    float4 v = {av.x + bv.x, av.y + bv.y, av.z + bv.z, av.w + bv.w};
    float s  = v.x + v.y + v.z + v.w;
    float s2 = v.x * v.x + v.y * v.y + v.z * v.z + v.w * v.w;
    #pragma unroll
    for (int m = 1; m < 64; m <<= 1) { s += __shfl_xor(s, m); s2 += __shfl_xor(s2, m); }
    float mu  = s * (1.f / 256.f);
    float var = s2 * (1.f / 256.f) - mu * mu;
    float rs  = rsqrtf(var + 1e-5f);
    float4 gv  = *(const float4*)(g + lane * 4);
    float4 bev = *(const float4*)(be + lane * 4);
    float4 o;
    o.x = (v.x - mu) * rs * gv.x + bev.x;
    o.y = (v.y - mu) * rs * gv.y + bev.y;
    o.z = (v.z - mu) * rs * gv.z + bev.z;
    o.w = (v.w - mu) * rs * gv.w + bev.w;
    *(float4*)(outf + base) = o;
    if (WRITE16) {
        ushort4 h4;
        h4.x = f2bf(o.x); h4.y = f2bf(o.y); h4.z = f2bf(o.z); h4.w = f2bf(o.w);
        *(ushort4*)(outh + base) = h4;
    }
}

// ---------------------------------------------------------------- launch
extern "C" void kernel_launch(void* const* d_in, const int* in_sizes, int n_in,
                              void* d_out, int out_size, void* d_ws, size_t ws_size,
                              hipStream_t stream) {
    const float* src  = (const float*)d_in[0];
    const float* pos  = (const float*)d_in[1];
    const float* rp   = (const float*)d_in[2];
    const float* Wv   = (const float*)d_in[5];  const float* bv   = (const float*)d_in[6];
    const float* Woff = (const float*)d_in[7];  const float* boff = (const float*)d_in[8];
    const float* Wa   = (const float*)d_in[9];  const float* ba   = (const float*)d_in[10];
    const float* Wo   = (const float*)d_in[11]; const float* bo   = (const float*)d_in[12];
    const float* W1   = (const float*)d_in[13]; const float* b1   = (const float*)d_in[14];
    const float* W2   = (const float*)d_in[15]; const float* b2   = (const float*)d_in[16];
    const float* g1   = (const float*)d_in[17]; const float* be1  = (const float*)d_in[18];
    const float* g2w  = (const float*)d_in[19]; const float* be2  = (const float*)d_in[20];

    char* ws = (char*)d_ws;
    // region map (bytes), ~225 MB total with reuse
    ushort* s16   = (ushort*)(ws + 0);            // 22,282,240
    ushort* q16   = (ushort*)(ws + 22282240);     // 22,282,240
    ushort* val16 = (ushort*)(ws + 44564480);     // 22,282,240 (bf16 value)
    float*  qout  = (float*)(ws + 66846720);      // 66,846,720 ([NROW][384]: offs|alog)
    ushort* def16 = (ushort*)(ws + 133693440);    // 22,282,240
    float*  x     = (float*)(ws + 155975680);     // 44,564,480
    ushort* x16   = (ushort*)(ws + 200540160);    // 22,282,240
    ushort* wts   = (ushort*)(ws + 222822400);    // 1,507,328 + 1,536
    float*  src2  = (float*)(ws + 0);             // reuse s16+q16 (dead after GEMMs)
    ushort* hid16 = (ushort*)(ws + 44564480);     // reuse val16+qout (89,128,960)
    float*  ff    = (float*)(ws + 0);             // reuse src2 (dead after LN1)

    ushort* WvT = wts;
    ushort* WqT = WvT + 65536;      // [384][256] (Woff|Wa)
    ushort* WoT = WqT + 98304;
    ushort* W1T = WoT + 65536;
    ushort* W2T = W1T + 262144;
    float*  bq  = (float*)(W2T + 262144);  // [384] = boff|ba

    wtrans_all<<<2946, 256, 0, stream>>>(Wv, Woff, Wa, Wo, W1, W2, boff, ba,
                                         WvT, WqT, WoT, W1T, W2T, bq);

    addpos_cast<<<2048, 256, 0, stream>>>(src, pos, s16, q16, NROW * CDIM / 4);

    dim3 grid4(NROW / 128, 4), grid6(NROW / 128, 6), grid16(NROW / 128, 16);
    gemm_bf16<0,1><<<grid4,  256, 0, stream>>>(s16, WvT, bv, nullptr, val16, 256, 256);
    gemm_bf16<0,0><<<grid6,  256, 0, stream>>>(q16, WqT, bq, qout,  nullptr, 256, 384);

    deform_attn<<<NROW / 4, 256, 0, stream>>>(val16, qout, rp, def16);

    gemm_bf16<0,0><<<grid4,  256, 0, stream>>>(def16, WoT, bo, src2, nullptr, 256, 256);
    resid_ln<1><<<NROW / 4, 256, 0, stream>>>(src, src2, g1, be1, x, x16);

    gemm_bf16<1,1><<<grid16, 256, 0, stream>>>(x16,   W1T, b1, nullptr, hid16, 256, 1024);
    gemm_bf16<0,0><<<grid4,  256, 0, stream>>>(hid16, W2T, b2, ff,   nullptr, 1024, 256);
    resid_ln<0><<<NROW / 4, 256, 0, stream>>>(x, ff, g2w, be2, (float*)d_out, nullptr);
}

// Round 6
// 311.087 us; speedup vs baseline: 2.5909x; 1.1629x over previous
//
#include <hip/hip_runtime.h>
#include <hip/hip_bf16.h>

// Problem constants (fixed by setup_inputs)
#define B_    2
#define LQ    21760
#define NROW  (B_*LQ)      // 43520 = 340*128
#define CDIM  256
#define DFF   1024

typedef __attribute__((ext_vector_type(8))) short bf16x8;
typedef __attribute__((ext_vector_type(4))) float f32x4;

static __device__ __forceinline__ ushort f2bf(float f) {
    union { float f; unsigned u; } v; v.f = f;
    unsigned u = v.u;
    return (ushort)((u + 0x7fffu + ((u >> 16) & 1u)) >> 16);
}
static __device__ __forceinline__ float u2f(unsigned u) {
    union { unsigned u; float f; } v; v.u = u; return v.f;
}
static __device__ __forceinline__ float bf2f(ushort h) {
    return u2f(((unsigned)h) << 16);
}
// chunk swizzle: permute 16B chunks within each 64-short K-block by row&7.
// Producers store with this; GEMM ds_read undoes it via byte^((lr&7)<<4).
static __device__ __forceinline__ int swzc(int row, int col) {
    return (col & ~63) | (col & 7) | ((((col >> 3) ^ row) & 7) << 3);
}
// global -> LDS direct (16B per lane)
static __device__ __forceinline__ void gload16(const void* g, void* l) {
    __builtin_amdgcn_global_load_lds(
        (const __attribute__((address_space(1))) unsigned*)g,
        (__attribute__((address_space(3))) unsigned*)l, 16, 0, 0);
}

// ---------------------------------------------------------------- elementwise
// q = src + pos; emit SWIZZLED bf16 copies of src and q (GEMM-A inputs)
__global__ void addpos_cast(const float* __restrict__ src, const float* __restrict__ pos,
                            ushort* __restrict__ s16, ushort* __restrict__ q16) {
    int i = blockIdx.x * blockDim.x + threadIdx.x;
    int stride = gridDim.x * blockDim.x;
    const float4* s4 = (const float4*)src;
    const float4* p4 = (const float4*)pos;
    const int n4 = NROW * 64;
    for (; i < n4; i += stride) {
        float4 s = s4[i], p = p4[i];
        ushort4 a, b;
        a.x = f2bf(s.x); a.y = f2bf(s.y); a.z = f2bf(s.z); a.w = f2bf(s.w);
        b.x = f2bf(s.x + p.x); b.y = f2bf(s.y + p.y);
        b.z = f2bf(s.z + p.z); b.w = f2bf(s.w + p.w);
        int row = i >> 6, col = (i & 63) * 4;
        int idx = row * 256 + swzc(row, col);
        *(ushort4*)(s16 + idx) = a;
        *(ushort4*)(q16 + idx) = b;
    }
}

// All weight transposes (swizzled) + concat bias in one launch.
static __device__ __forceinline__ void wt_one(const float* W, ushort* Wt, int K, int N, int i) {
    int n = i / K, k = i - n * K;
    Wt[(size_t)n * K + swzc(n, k)] = f2bf(W[(size_t)k * N + n]);
}
__global__ void wtrans_all(const float* Wv, const float* Woff, const float* Wa,
                           const float* Wo, const float* W1, const float* W2,
                           const float* boff, const float* ba,
                           ushort* WvT, ushort* WqT, ushort* WoT,
                           ushort* W1T, ushort* W2T, float* bq) {
    int gid = blockIdx.x * 256 + threadIdx.x;   // 2946*256 = 754176 >= 754048
    if (gid < 65536)  { wt_one(Wv, WvT, 256, 256, gid); return; }
    if (gid < 163840) {                // WqT[384][256]: Woff cols 0..255, Wa cols 256..383
        int i = gid - 65536;
        int n = i >> 8, k = i & 255;
        float v = (n < 256) ? Woff[(size_t)k * 256 + n] : Wa[(size_t)k * 128 + (n - 256)];
        WqT[n * 256 + swzc(n, k)] = f2bf(v);
        return;
    }
    if (gid < 229376) { wt_one(Wo, WoT, 256, 256,  gid - 163840); return; }
    if (gid < 491520) { wt_one(W1, W1T, 256, 1024, gid - 229376); return; }
    if (gid < 753664) { wt_one(W2, W2T, 1024, 256, gid - 491520); return; }
    if (gid < 754048) {
        int i = gid - 753664;
        bq[i] = (i < 256) ? boff[i] : ba[i - 256];
    }
}

// ---------------------------------------------------------------- GEMM (m97 structure)
// C[M][N] = A[M][K]*B[K][N] (+bias, opt relu). A,Bt chunk-swizzled bf16; Bt=B^T [N][K].
// 128x128 tile, BK=64, 4 waves (2x2), per-wave 64x64 via 4x4 16x16x32 MFMA frags.
// Staging via global_load_lds (16B/lane), linear LDS, swizzled ds_read.
template<int RELU, int OUTBF16, int SWZOUT>
__global__ __launch_bounds__(256) void gemm_bf16(
    const ushort* __restrict__ A, const ushort* __restrict__ Bt,
    const float* __restrict__ bias,
    float* __restrict__ Cf, ushort* __restrict__ Ch, int K, int N) {
    __shared__ __align__(16) ushort As[128 * 64];
    __shared__ __align__(16) ushort Bs[128 * 64];
    const int tid  = threadIdx.x;
    const int bm   = blockIdx.x * 128;
    const int bn   = blockIdx.y * 128;
    const int w    = tid >> 6, lane = tid & 63;
    const int wm   = (w >> 1) * 64, wn = (w & 1) * 64;
    const int lr   = lane & 15, lk = lane >> 4;
    const int srow = tid >> 3;            // 0..31
    const int sch  = tid & 7;             // 16B chunk

    f32x4 acc[4][4] = {};

    const ushort* Ab = A  + (size_t)(bm + srow) * K + sch * 8;
    const ushort* Bb = Bt + (size_t)(bn + srow) * K + sch * 8;
    ushort* Asd = &As[srow * 64 + sch * 8];
    ushort* Bsd = &Bs[srow * 64 + sch * 8];

    for (int k0 = 0; k0 < K; k0 += 64) {
        #pragma unroll
        for (int c = 0; c < 4; c++)
            gload16(Ab + (size_t)c * 32 * K + k0, Asd + c * 2048);
        #pragma unroll
        for (int c = 0; c < 4; c++)
            gload16(Bb + (size_t)c * 32 * K + k0, Bsd + c * 2048);
        __syncthreads();
        #pragma unroll
        for (int ks = 0; ks < 2; ks++) {
            bf16x8 af[4], bfr[4];
            #pragma unroll
            for (int m = 0; m < 4; m++) {
                int row = wm + m * 16 + lr;
                int byte = (row * 128 + ks * 64 + lk * 16) ^ ((lr & 7) << 4);
                af[m] = *(const bf16x8*)((const char*)As + byte);
            }
            #pragma unroll
            for (int n = 0; n < 4; n++) {
                int row = wn + n * 16 + lr;
                int byte = (row * 128 + ks * 64 + lk * 16) ^ ((lr & 7) << 4);
                bfr[n] = *(const bf16x8*)((const char*)Bs + byte);
            }
            #pragma unroll
            for (int m = 0; m < 4; m++)
                #pragma unroll
                for (int n = 0; n < 4; n++)
                    acc[m][n] = __builtin_amdgcn_mfma_f32_16x16x32_bf16(af[m], bfr[n], acc[m][n], 0, 0, 0);
        }
        __syncthreads();
    }
    // Epilogue. D: col = lane&15, row = (lane>>4)*4 + i
    #pragma unroll
    for (int m = 0; m < 4; m++) {
        int row = bm + wm + m * 16 + lk * 4;
        #pragma unroll
        for (int n = 0; n < 4; n++) {
            int col = bn + wn + n * 16 + lr;
            float bb = bias ? bias[col] : 0.f;
            #pragma unroll
            for (int i = 0; i < 4; i++) {
                float v = acc[m][n][i] + bb;
                if (RELU) v = v > 0.f ? v : 0.f;
                if (OUTBF16) {
                    int cc = SWZOUT ? swzc(row + i, col) : col;
                    Ch[(size_t)(row + i) * N + cc] = f2bf(v);
                } else {
                    Cf[(size_t)(row + i) * N + col] = v;
                }
            }
        }
    }
}

// ---------------------------------------------------------------- deform attn
// 1 wave per (b,query) row; 4 rows per block.
// Phase A: lane = h*8+j computes points {2j,2j+1} of head h -> LDS records {off,wgt}
// Phase B: lane = h*8+c4 gathers 64 corners for channels [c4*4, c4*4+4)
__global__ __launch_bounds__(256) void deform_attn(
    const ushort* __restrict__ val16,  // [B][LQ][256] bf16 linear
    const ushort* __restrict__ qout,   // [NROW][384] bf16: [0,256)=offs, [256,384)=logits
    const float* __restrict__ rp,      // [NROW][4][2]
    ushort* __restrict__ out16) {      // [NROW][256] bf16 SWIZZLED
    __shared__ uint2 rec[4][8][66];    // 66 = 64 records + 2 pad
    const int wid  = threadIdx.x >> 6;
    const int row  = blockIdx.x * 4 + wid;
    const int lane = threadIdx.x & 63;
    const int h    = lane >> 3;
    const int j    = lane & 7;
    const int b    = row / LQ;

    const ushort* qrow = qout + (size_t)row * 384;

    // ---- phase A: softmax (8-lane group reduce) + 2 points per lane
    unsigned lgu = *(const unsigned*)(qrow + 256 + h * 16 + j * 2);
    float lgx = u2f(lgu << 16), lgy = u2f(lgu & 0xffff0000u);
    float m = fmaxf(lgx, lgy);
    m = fmaxf(m, __shfl_xor(m, 1, 8));
    m = fmaxf(m, __shfl_xor(m, 2, 8));
    m = fmaxf(m, __shfl_xor(m, 4, 8));
    float e0 = __expf(lgx - m), e1 = __expf(lgy - m);
    float s = e0 + e1;
    s += __shfl_xor(s, 1, 8);
    s += __shfl_xor(s, 2, 8);
    s += __shfl_xor(s, 4, 8);
    const float inv = 1.f / s;

    const int L  = j >> 1;              // both points of this lane share a level
    const int Wl = 128 >> L;
    const int s0 = (L == 0) ? 0 : (L == 1) ? 16384 : (L == 2) ? 20480 : 21504;
    const float fW = (float)Wl;
    float2 rr = *(const float2*)(rp + (size_t)row * 8 + L * 2);
    uint2 ou  = *(const uint2*)(qrow + h * 32 + j * 4);
    float oxv[2] = { u2f(ou.x << 16), u2f(ou.y << 16) };
    float oyv[2] = { u2f(ou.x & 0xffff0000u), u2f(ou.y & 0xffff0000u) };
    float ev[2]  = { e0, e1 };

    #pragma unroll
    for (int pt = 0; pt < 2; pt++) {
        float aw = ev[pt] * inv;
        float x = rr.x * fW + oxv[pt] - 0.5f;
        float y = rr.y * fW + oyv[pt] - 0.5f;
        float xf = floorf(x), yf = floorf(y);
        float lx = x - xf, ly = y - yf;
        int x0 = (int)xf, y0 = (int)yf;
        int x1 = x0 + 1, y1 = y0 + 1;
        int x0c = min(max(x0, 0), Wl - 1), x1c = min(max(x1, 0), Wl - 1);
        int y0c = min(max(y0, 0), Wl - 1), y1c = min(max(y1, 0), Wl - 1);
        bool vx0 = (unsigned)x0 < (unsigned)Wl, vx1 = (unsigned)x1 < (unsigned)Wl;
        bool vy0 = (unsigned)y0 < (unsigned)Wl, vy1 = (unsigned)y1 < (unsigned)Wl;
        float wx1 = lx, wx0 = 1.f - lx, wy1 = ly, wy0 = 1.f - ly;
        float w00 = (vy0 & vx0) ? aw * wy0 * wx0 : 0.f;
        float w01 = (vy0 & vx1) ? aw * wy0 * wx1 : 0.f;
        float w10 = (vy1 & vx0) ? aw * wy1 * wx0 : 0.f;
        float w11 = (vy1 & vx1) ? aw * wy1 * wx1 : 0.f;
        unsigned hb = (unsigned)h * 64u;
        unsigned o00 = (unsigned)(s0 + y0c * Wl + x0c) * 512u + hb;
        unsigned o01 = (unsigned)(s0 + y0c * Wl + x1c) * 512u + hb;
        unsigned o10 = (unsigned)(s0 + y1c * Wl + x0c) * 512u + hb;
        unsigned o11 = (unsigned)(s0 + y1c * Wl + x1c) * 512u + hb;
        uint4* dst = (uint4*)&rec[wid][h][(j * 2 + pt) * 4];
        dst[0] = make_uint4(o00, __float_as_uint(w00), o01, __float_as_uint(w01));
        dst[1] = make_uint4(o10, __float_as_uint(w10), o11, __float_as_uint(w11));
    }
    __syncthreads();

    // ---- phase B: gather. c4 = j
    const int bu = __builtin_amdgcn_readfirstlane(b);  // wave-uniform -> SGPR base
    const char* ubase = (const char*)val16 + (size_t)bu * (LQ * 512);
    const unsigned coff = (unsigned)j * 8u;
    const uint2* r = &rec[wid][h][0];
    float a0 = 0.f, a1 = 0.f, a2 = 0.f, a3 = 0.f;
    #pragma unroll 16
    for (int i = 0; i < 64; i++) {
        uint2 rw = r[i];
        float wgt = u2f(rw.y);
        uint2 uu = *(const uint2*)(ubase + (rw.x + coff));
        a0 += wgt * u2f(uu.x << 16);
        a1 += wgt * u2f(uu.x);      // low 16 bits are sub-2^-8 mantissa noise: ok
        a2 += wgt * u2f(uu.y << 16);
        a3 += wgt * u2f(uu.y);
    }
    ushort4 o4;
    o4.x = f2bf(a0); o4.y = f2bf(a1);
    o4.z = f2bf(a2); o4.w = f2bf(a3);
    int col = h * 32 + j * 4;
    *(ushort4*)(out16 + (size_t)row * 256 + swzc(row, col)) = o4;
}

// ---------------------------------------------------------------- residual + LN
// LN1: x16 = swz(LN(src + src2_16)); 1 wave/row, 4 rows/block
__global__ __launch_bounds__(256) void resid_ln1(
    const float* __restrict__ a, const ushort* __restrict__ b,
    const float* __restrict__ g, const float* __restrict__ be,
    ushort* __restrict__ outh) {
    const int w = threadIdx.x >> 6, lane = threadIdx.x & 63;
    const int row = blockIdx.x * 4 + w;
    const size_t base = (size_t)row * 256 + lane * 4;
    float4 av = *(const float4*)(a + base);
    ushort4 bv = *(const ushort4*)(b + base);
    float4 v = {av.x + bf2f(bv.x), av.y + bf2f(bv.y), av.z + bf2f(bv.z), av.w + bf2f(bv.w)};
    float s  = v.x + v.y + v.z + v.w;
    float s2 = v.x * v.x + v.y * v.y + v.z * v.z + v.w * v.w;
    #pragma unroll
    for (int m = 1; m < 64; m <<= 1) { s += __shfl_xor(s, m); s2 += __shfl_xor(s2, m); }
    float mu  = s * (1.f / 256.f);
    float var = s2 * (1.f / 256.f) - mu * mu;
    float rs  = rsqrtf(var + 1e-5f);
    float4 gv  = *(const float4*)(g + lane * 4);
    float4 bev = *(const float4*)(be + lane * 4);
    ushort4 h4;
    h4.x = f2bf((v.x - mu) * rs * gv.x + bev.x);
    h4.y = f2bf((v.y - mu) * rs * gv.y + bev.y);
    h4.z = f2bf((v.z - mu) * rs * gv.z + bev.z);
    h4.w = f2bf((v.w - mu) * rs * gv.w + bev.w);
    *(ushort4*)(outh + (size_t)row * 256 + swzc(row, lane * 4)) = h4;
}

// LN2: out = LN(deswz(x16) + ff)
__global__ __launch_bounds__(256) void resid_ln2(
    const ushort* __restrict__ a, const float* __restrict__ b,
    const float* __restrict__ g, const float* __restrict__ be,
    float* __restrict__ outf) {
    const int w = threadIdx.x >> 6, lane = threadIdx.x & 63;
    const int row = blockIdx.x * 4 + w;
    const size_t base = (size_t)row * 256 + lane * 4;
    ushort4 av = *(const ushort4*)(a + (size_t)row * 256 + swzc(row, lane * 4));
    float4 bv = *(const float4*)(b + base);
    float4 v = {bf2f(av.x) + bv.x, bf2f(av.y) + bv.y, bf2f(av.z) + bv.z, bf2f(av.w) + bv.w};
    float s  = v.x + v.y + v.z + v.w;
    float s2 = v.x * v.x + v.y * v.y + v.z * v.z + v.w * v.w;
    #pragma unroll
    for (int m = 1; m < 64; m <<= 1) { s += __shfl_xor(s, m); s2 += __shfl_xor(s2, m); }
    float mu  = s * (1.f / 256.f);
    float var = s2 * (1.f / 256.f) - mu * mu;
    float rs  = rsqrtf(var + 1e-5f);
    float4 gv  = *(const float4*)(g + lane * 4);
    float4 bev = *(const float4*)(be + lane * 4);
    float4 o;
    o.x = (v.x - mu) * rs * gv.x + bev.x;
    o.y = (v.y - mu) * rs * gv.y + bev.y;
    o.z = (v.z - mu) * rs * gv.z + bev.z;
    o.w = (v.w - mu) * rs * gv.w + bev.w;
    *(float4*)(outf + base) = o;
}

// ---------------------------------------------------------------- launch
extern "C" void kernel_launch(void* const* d_in, const int* in_sizes, int n_in,
                              void* d_out, int out_size, void* d_ws, size_t ws_size,
                              hipStream_t stream) {
    const float* src  = (const float*)d_in[0];
    const float* pos  = (const float*)d_in[1];
    const float* rp   = (const float*)d_in[2];
    const float* Wv   = (const float*)d_in[5];  const float* bv   = (const float*)d_in[6];
    const float* Woff = (const float*)d_in[7];  const float* boff = (const float*)d_in[8];
    const float* Wa   = (const float*)d_in[9];  const float* ba   = (const float*)d_in[10];
    const float* Wo   = (const float*)d_in[11]; const float* bo   = (const float*)d_in[12];
    const float* W1   = (const float*)d_in[13]; const float* b1   = (const float*)d_in[14];
    const float* W2   = (const float*)d_in[15]; const float* b2   = (const float*)d_in[16];
    const float* g1   = (const float*)d_in[17]; const float* be1  = (const float*)d_in[18];
    const float* g2w  = (const float*)d_in[19]; const float* be2  = (const float*)d_in[20];

    char* ws = (char*)d_ws;
    // region map (bytes), ~169 MB total with reuse
    ushort* s16    = (ushort*)(ws + 0);            // 22,282,240 (swz)
    ushort* q16    = (ushort*)(ws + 22282240);     // 22,282,240 (swz)
    ushort* val16  = (ushort*)(ws + 44564480);     // 22,282,240 (linear)
    ushort* qout16 = (ushort*)(ws + 66846720);     // 33,423,360 (linear, [NROW][384])
    ushort* def16  = (ushort*)(ws + 100270080);    // 22,282,240 (swz)
    ushort* src2_16= (ushort*)(ws + 122552320);    // 22,282,240 (linear)
    ushort* x16    = (ushort*)(ws + 144834560);    // 22,282,240 (swz)
    ushort* wts    = (ushort*)(ws + 167116800);    // 1,507,328 + 1,536
    ushort* hid16  = (ushort*)(ws + 44564480);     // reuse val16..src2_16 (swz, 89,128,960)
    float*  ff     = (float*)(ws + 0);             // reuse s16+q16 (44,564,480)

    ushort* WvT = wts;
    ushort* WqT = WvT + 65536;      // [384][256] (Woff|Wa)
    ushort* WoT = WqT + 98304;
    ushort* W1T = WoT + 65536;
    ushort* W2T = W1T + 262144;
    float*  bq  = (float*)(W2T + 262144);  // [384] = boff|ba

    wtrans_all<<<2946, 256, 0, stream>>>(Wv, Woff, Wa, Wo, W1, W2, boff, ba,
                                         WvT, WqT, WoT, W1T, W2T, bq);

    addpos_cast<<<2048, 256, 0, stream>>>(src, pos, s16, q16);

    dim3 gv2(NROW / 128, 2), gq3(NROW / 128, 3), gf8(NROW / 128, 8);
    gemm_bf16<0,1,0><<<gv2, 256, 0, stream>>>(s16, WvT, bv, nullptr, val16,  256, 256);
    gemm_bf16<0,1,0><<<gq3, 256, 0, stream>>>(q16, WqT, bq, nullptr, qout16, 256, 384);

    deform_attn<<<NROW / 4, 256, 0, stream>>>(val16, qout16, rp, def16);

    gemm_bf16<0,1,0><<<gv2, 256, 0, stream>>>(def16, WoT, bo, nullptr, src2_16, 256, 256);
    resid_ln1<<<NROW / 4, 256, 0, stream>>>(src, src2_16, g1, be1, x16);

    gemm_bf16<1,1,1><<<gf8, 256, 0, stream>>>(x16,   W1T, b1, nullptr, hid16, 256, 1024);
    gemm_bf16<0,0,0><<<gv2, 256, 0, stream>>>(hid16, W2T, b2, ff,   nullptr, 1024, 256);
    resid_ln2<<<NROW / 4, 256, 0, stream>>>(x16, ff, g2w, be2, (float*)d_out);
}